// Round 6
// baseline (749.945 us; speedup 1.0000x reference)
//
#include <hip/hip_runtime.h>
#include <hip/hip_bf16.h>
#include <cstddef>

#define NODES  100000
#define EDGES  3200000
#define ETOT   3300000   // EDGES + NODES self-loops
#define NGRAPH 64
#define HDIM   256
#define BSHIFT 9
#define NBUCK  196       // ceil(NODES / 512)
#define BCAP   19456     // records/bucket: mean 16896 + 20 sigma

// feature arrays stored as packed column SLABS of 32 cols (3.2 MB each).
// aggregation runs ONE slab per kernel launch -> slab is L2-resident on
// every XCD -> random gathers become L2 hits.
#define SLABSZ ((size_t)NODES * 32)

typedef __hip_bfloat16 bf16;
typedef short bf16x8 __attribute__((ext_vector_type(8)));
typedef float f32x4 __attribute__((ext_vector_type(4)));
typedef float f32x2 __attribute__((ext_vector_type(2)));
typedef unsigned u32x2 __attribute__((ext_vector_type(2)));
typedef unsigned u32x4 __attribute__((ext_vector_type(4)));

// ---------------------------------------------------------------- fp32 -> fp8 of x, pre-scaled by dinv[row]
// writes SLICED x8 (4 slabs of 32 cols)
__global__ void xcast_kernel(const float* __restrict__ x, const float* __restrict__ dinv,
                             unsigned char* __restrict__ x8) {
    int i = blockIdx.x * 256 + threadIdx.x;            // 4 elements each
    if ((size_t)i * 4 >= (size_t)NODES * 128) return;
    int r = i >> 5;                                    // row
    float d = dinv[r];
    float4 v = *(const float4*)(x + (size_t)i * 4);
    int w = __builtin_amdgcn_cvt_pk_fp8_f32(v.x * d, v.y * d, 0, false);
    w     = __builtin_amdgcn_cvt_pk_fp8_f32(v.z * d, v.w * d, w, true);
    // col = (i&31)*4 -> slab (i&31)>>3, in-slab byte r*32 + (i&7)*4
    *(unsigned*)(x8 + (size_t)((i & 31) >> 3) * SLABSZ + (size_t)r * 32 + (i & 7) * 4) = (unsigned)w;
}

// ---------------------------------------------------------------- W1/W2 -> transposed bf16
__global__ void wcast_kernel(const float* __restrict__ W1, const float* __restrict__ W2,
                             bf16* __restrict__ W1t, bf16* __restrict__ W2t) {
    int i = blockIdx.x * 256 + threadIdx.x;
    if (i < 128 * 256) {
        int n = i / 128, k = i - n * 128;
        W1t[i] = __float2bfloat16(W1[(size_t)k * 256 + n]);
    } else if (i < 128 * 256 + 256 * 256) {
        int q = i - 128 * 256;
        int n = q / 256, k = q - n * 256;
        W2t[q] = __float2bfloat16(W2[(size_t)k * 256 + n]);
    }
}

// ---------------------------------------------------------------- fill phase 1: 4-byte bucket records
__global__ __launch_bounds__(1024) void fillp1_kernel(const int* __restrict__ row,
                                                      const int* __restrict__ col,
                                                      int* __restrict__ gcnt,
                                                      unsigned* __restrict__ recs) {
    __shared__ int hist[4][NBUCK];
    __shared__ int coff[4][NBUCK];
    __shared__ int base[NBUCK];
    int t  = threadIdx.x;
    int cp = t & 3;
    for (int i = t; i < 4 * NBUCK; i += 1024) ((int*)hist)[i] = 0;
    __syncthreads();
    int e0 = blockIdx.x * 16384;
    int r[16], c[16], rk[16];
    #pragma unroll
    for (int i = 0; i < 16; i++) {
        int e = e0 + i * 1024 + t;
        r[i] = -1;
        if (e < ETOT) {
            if (e < EDGES) { r[i] = row[e]; c[i] = col[e]; }
            else           { r[i] = e - EDGES; c[i] = r[i]; }
            rk[i] = atomicAdd(&hist[cp][c[i] >> BSHIFT], 1);
        }
    }
    __syncthreads();
    if (t < NBUCK) {
        int h0 = hist[0][t], h1 = hist[1][t], h2 = hist[2][t], h3 = hist[3][t];
        coff[0][t] = 0; coff[1][t] = h0; coff[2][t] = h0 + h1; coff[3][t] = h0 + h1 + h2;
        int tot = h0 + h1 + h2 + h3;
        base[t] = (tot > 0) ? atomicAdd(&gcnt[t], tot) : 0;
    }
    __syncthreads();
    #pragma unroll
    for (int i = 0; i < 16; i++) {
        if (r[i] >= 0) {
            int b = c[i] >> BSHIFT;
            recs[(size_t)b * BCAP + base[b] + coff[cp][b] + rk[i]] =
                ((unsigned)r[i] << BSHIFT) | (unsigned)(c[i] & 511);
        }
    }
}

// ---------------------------------------------------------------- per-bucket counting sort
__global__ __launch_bounds__(256) void build_kernel(const unsigned* __restrict__ recs,
                                                    const int* __restrict__ gcnt,
                                                    int* __restrict__ rowptr,
                                                    float* __restrict__ dinv,
                                                    int* __restrict__ csr) {
    __shared__ int hist[512];
    __shared__ int cur[512];
    __shared__ int part[256];
    __shared__ int sbase;
    const int b = blockIdx.x, t = threadIdx.x;
    const int cnt = gcnt[b];
    const int n0 = b << BSHIFT;
    part[t] = (t < b) ? gcnt[t] : 0;     // b < NBUCK <= 256
    __syncthreads();
    for (int off = 128; off >= 1; off >>= 1) {
        if (t < off) part[t] += part[t + off];
        __syncthreads();
    }
    if (t == 0) sbase = part[0];
    __syncthreads();
    const int base = sbase;
    hist[t] = 0; hist[t + 256] = 0;
    __syncthreads();
    const unsigned* rb = recs + (size_t)b * BCAP;
    for (int i = t; i < cnt; i += 256) atomicAdd(&hist[rb[i] & 511u], 1);
    __syncthreads();
    int h0 = hist[2 * t], h1 = hist[2 * t + 1];
    part[t] = h0 + h1;
    __syncthreads();
    for (int off = 1; off < 256; off <<= 1) {
        int v = (t >= off) ? part[t - off] : 0;
        __syncthreads();
        part[t] += v;
        __syncthreads();
    }
    int ex = (t == 0) ? 0 : part[t - 1];       // exclusive over node pairs
    cur[2 * t]     = ex;
    cur[2 * t + 1] = ex + h0;
    int v0 = n0 + 2 * t, v1 = v0 + 1;
    if (v0 < NODES) { rowptr[v0] = base + ex;      dinv[v0] = rsqrtf((float)h0); }
    if (v1 < NODES) { rowptr[v1] = base + ex + h0; dinv[v1] = rsqrtf((float)h1); }
    if (b == 0 && t == 0) rowptr[NODES] = ETOT;
    __syncthreads();
    for (int i = t; i < cnt; i += 256) {
        unsigned r = rb[i];
        int pos = atomicAdd(&cur[r & 511u], 1);
        csr[base + pos] = (int)(r >> BSHIFT);
    }
}

#define ACC16(q) do {                                                      \
        a[0] += __builtin_amdgcn_cvt_pk_f32_fp8((int)(q).x, false);        \
        a[1] += __builtin_amdgcn_cvt_pk_f32_fp8((int)(q).x, true);         \
        a[2] += __builtin_amdgcn_cvt_pk_f32_fp8((int)(q).y, false);        \
        a[3] += __builtin_amdgcn_cvt_pk_f32_fp8((int)(q).y, true);         \
        a[4] += __builtin_amdgcn_cvt_pk_f32_fp8((int)(q).z, false);        \
        a[5] += __builtin_amdgcn_cvt_pk_f32_fp8((int)(q).z, true);         \
        a[6] += __builtin_amdgcn_cvt_pk_f32_fp8((int)(q).w, false);        \
        a[7] += __builtin_amdgcn_cvt_pk_f32_fp8((int)(q).w, true);         \
    } while (0)

// ---------------------------------------------------------------- slab pull aggregation (ONE 3.2MB slab/launch)
// Lane-owns-node: 2 lanes per node, each lane owns 16B of the 32B slice and
// serially walks its node's csr list with an 8-deep gather pipeline.
// dst fp8 = dinv[v] * sum_s src[s]  (src pre-scaled by dinv[s])
__global__ __launch_bounds__(256) void aggs_kernel(const unsigned char* __restrict__ src,
                                                   const int* __restrict__ rowptr,
                                                   const int* __restrict__ csr,
                                                   const float* __restrict__ dinv,
                                                   unsigned char* __restrict__ dst) {
    int idx  = blockIdx.x * 256 + threadIdx.x;
    int node = idx >> 1;
    if (node >= NODES) return;
    int pos = (idx & 1) * 16;                          // 16B half of the 32B slice
    int beg = rowptr[node], end = rowptr[node + 1];
    float d = dinv[node];
    f32x2 a[8] = {};
    int j = beg;
    int nb = (end - beg) >> 3;
    if (nb > 0) {
        int s0 = __builtin_nontemporal_load(csr + j + 0);
        int s1 = __builtin_nontemporal_load(csr + j + 1);
        int s2 = __builtin_nontemporal_load(csr + j + 2);
        int s3 = __builtin_nontemporal_load(csr + j + 3);
        int s4 = __builtin_nontemporal_load(csr + j + 4);
        int s5 = __builtin_nontemporal_load(csr + j + 5);
        int s6 = __builtin_nontemporal_load(csr + j + 6);
        int s7 = __builtin_nontemporal_load(csr + j + 7);
        for (int b = 1; b <= nb; ++b) {
            u32x4 q0 = *(const u32x4*)(src + (size_t)s0 * 32 + pos);
            u32x4 q1 = *(const u32x4*)(src + (size_t)s1 * 32 + pos);
            u32x4 q2 = *(const u32x4*)(src + (size_t)s2 * 32 + pos);
            u32x4 q3 = *(const u32x4*)(src + (size_t)s3 * 32 + pos);
            u32x4 q4 = *(const u32x4*)(src + (size_t)s4 * 32 + pos);
            u32x4 q5 = *(const u32x4*)(src + (size_t)s5 * 32 + pos);
            u32x4 q6 = *(const u32x4*)(src + (size_t)s6 * 32 + pos);
            u32x4 q7 = *(const u32x4*)(src + (size_t)s7 * 32 + pos);
            j += 8;
            if (b < nb) {
                s0 = __builtin_nontemporal_load(csr + j + 0);
                s1 = __builtin_nontemporal_load(csr + j + 1);
                s2 = __builtin_nontemporal_load(csr + j + 2);
                s3 = __builtin_nontemporal_load(csr + j + 3);
                s4 = __builtin_nontemporal_load(csr + j + 4);
                s5 = __builtin_nontemporal_load(csr + j + 5);
                s6 = __builtin_nontemporal_load(csr + j + 6);
                s7 = __builtin_nontemporal_load(csr + j + 7);
            }
            ACC16(q0); ACC16(q1); ACC16(q2); ACC16(q3);
            ACC16(q4); ACC16(q5); ACC16(q6); ACC16(q7);
        }
    }
    for (; j < end; ++j) {
        int s = __builtin_nontemporal_load(csr + j);
        u32x4 q = *(const u32x4*)(src + (size_t)s * 32 + pos);
        ACC16(q);
    }
    u32x4 o;
    int p;
    p = __builtin_amdgcn_cvt_pk_fp8_f32(a[0].x * d, a[0].y * d, 0, false);
    p = __builtin_amdgcn_cvt_pk_fp8_f32(a[1].x * d, a[1].y * d, p, true);
    o.x = (unsigned)p;
    p = __builtin_amdgcn_cvt_pk_fp8_f32(a[2].x * d, a[2].y * d, 0, false);
    p = __builtin_amdgcn_cvt_pk_fp8_f32(a[3].x * d, a[3].y * d, p, true);
    o.y = (unsigned)p;
    p = __builtin_amdgcn_cvt_pk_fp8_f32(a[4].x * d, a[4].y * d, 0, false);
    p = __builtin_amdgcn_cvt_pk_fp8_f32(a[5].x * d, a[5].y * d, p, true);
    o.z = (unsigned)p;
    p = __builtin_amdgcn_cvt_pk_fp8_f32(a[6].x * d, a[6].y * d, 0, false);
    p = __builtin_amdgcn_cvt_pk_fp8_f32(a[7].x * d, a[7].y * d, p, true);
    o.w = (unsigned)p;
    *(u32x4*)(dst + (size_t)node * 32 + pos) = o;
}
#undef ACC16

// ---------------------------------------------------------------- MFMA GEMM 128x128, fp8 A (sliced, decoded), bf16 B
// C[M,256] = relu(A8[M,K] @ B[K,256] + bias) [* dinv[row] if PRESCALE], written fp8 e4m3.
// A8 is column-sliced (K/32 slabs). C written sliced if SPLITC (consumed by aggs), else row-major.
template <int K, bool PRESCALE, bool SPLITC>
__global__ __launch_bounds__(256) void mgemm_kernel(const unsigned char* __restrict__ A8,
                                                    const bf16* __restrict__ Bt,
                                                    const float* __restrict__ bias,
                                                    const float* __restrict__ dinv,
                                                    unsigned char* __restrict__ C8) {
    __shared__ short As[128][40];   // [m][k] bf16 (decoded from fp8), +8 pad
    __shared__ short Bs[128][40];   // [n][k] bf16
    const int t    = threadIdx.x;
    const int bm   = (int)(blockIdx.x >> 1) * 128;
    const int bn   = (int)(blockIdx.x & 1) * 128;
    const int lane = t & 63;
    const int wave = t >> 6;
    const int wm   = (wave >> 1) * 64, wn = (wave & 1) * 64;
    const int m16  = lane & 15, kq = lane >> 4;
    f32x4 acc[4][4] = {};

    for (int k0 = 0; k0 < K; k0 += 32) {
        // A tile: 128 rows x 32 fp8 = 4 KB from slab k0>>5 (fully contiguous), decode -> bf16 LDS
        {
            int rr = t >> 1, seg = t & 1;          // seg*16 fp8 within the 32-k slice
            uint4 va = {0u, 0u, 0u, 0u};
            int grow = bm + rr;
            if (grow < NODES)
                va = *(const uint4*)(A8 + (size_t)(k0 >> 5) * SLABSZ + (size_t)grow * 32 + seg * 16);
            unsigned wd[4] = {va.x, va.y, va.z, va.w};
            #pragma unroll
            for (int u = 0; u < 4; u++) {
                f32x2 lo = __builtin_amdgcn_cvt_pk_f32_fp8((int)wd[u], false);
                f32x2 hi = __builtin_amdgcn_cvt_pk_f32_fp8((int)wd[u], true);
                union { __hip_bfloat162 h[2]; u32x2 q; } pk;
                pk.h[0] = __float22bfloat162_rn(make_float2(lo.x, lo.y));
                pk.h[1] = __float22bfloat162_rn(make_float2(hi.x, hi.y));
                *(u32x2*)&As[rr][seg * 16 + u * 4] = pk.q;
            }
        }
        // B tile: 128 n-rows x 32 k bf16 = 8 KB, two uint4 per thread
        #pragma unroll
        for (int h = 0; h < 2; h++) {
            int q = t * 2 + h;
            int rr = q >> 2, seg = q & 3;
            uint4 vb = *(const uint4*)(Bt + (size_t)(bn + rr) * K + k0 + seg * 8);
            *(uint4*)&Bs[rr][seg * 8] = vb;
        }
        __syncthreads();
        bf16x8 af[4], bf_[4];
        #pragma unroll
        for (int i = 0; i < 4; i++) {
            af[i]  = *(const bf16x8*)&As[wm + i * 16 + m16][kq * 8];
            bf_[i] = *(const bf16x8*)&Bs[wn + i * 16 + m16][kq * 8];
        }
        #pragma unroll
        for (int mt = 0; mt < 4; mt++)
            #pragma unroll
            for (int nt = 0; nt < 4; nt++)
                acc[mt][nt] = __builtin_amdgcn_mfma_f32_16x16x32_bf16(af[mt], bf_[nt],
                                                                     acc[mt][nt], 0, 0, 0);
        __syncthreads();
    }

    // C/D layout: col = lane&15, row = (lane>>4)*4 + reg
    #pragma unroll
    for (int mt = 0; mt < 4; mt++) {
        #pragma unroll
        for (int r = 0; r < 4; r++) {
            int row = bm + wm + mt * 16 + kq * 4 + r;
            if (row >= NODES) continue;
            float sc = PRESCALE ? dinv[row] : 1.f;
            #pragma unroll
            for (int nt = 0; nt < 4; nt++) {
                int colb = bn + wn + nt * 16 + m16;
                float v = fmaxf(acc[mt][nt][r] + bias[colb], 0.f) * sc;
                int pkd = __builtin_amdgcn_cvt_pk_fp8_f32(v, v, 0, false);
                unsigned char byte = (unsigned char)(pkd & 0xff);
                if (SPLITC)
                    C8[(size_t)(colb >> 5) * SLABSZ + (size_t)row * 32 + (colb & 31)] = byte;
                else
                    C8[(size_t)row * 256 + colb] = byte;
            }
        }
    }
}

// ---------------------------------------------------------------- segmented mean-pool sum (fp8 in, row-major)
// 128 rows/block, 32 rows/wave; lane covers 4 cols. Fast path when the wave's
// whole row-range is one graph (~98% of waves): branch-free unrolled loop.
__global__ __launch_bounds__(256) void pool_kernel(const unsigned char* __restrict__ h2,
                                                   const int* __restrict__ batch,
                                                   float* __restrict__ sums) {
    int lane = threadIdx.x & 63;                   // 4 cols each
    int wv   = threadIdx.x >> 6;                   // 0..3
    int r0   = blockIdx.x * 128 + wv * 32;
    if (r0 >= NODES) return;
    int r1 = r0 + 32; if (r1 > NODES) r1 = NODES;
    float a0 = 0.f, a1 = 0.f, a2 = 0.f, a3 = 0.f;
    int cb = lane * 4;
    int gfirst = batch[r0], glast = batch[r1 - 1];
    if (gfirst == glast) {
        #pragma unroll 4
        for (int r = r0; r < r1; r++) {
            unsigned q = *(const unsigned*)(h2 + (size_t)r * 256 + cb);
            f32x2 d0 = __builtin_amdgcn_cvt_pk_f32_fp8((int)q, false);
            f32x2 d1 = __builtin_amdgcn_cvt_pk_f32_fp8((int)q, true);
            a0 += d0.x; a1 += d0.y; a2 += d1.x; a3 += d1.y;
        }
        atomicAdd(&sums[gfirst * 256 + cb + 0], a0);
        atomicAdd(&sums[gfirst * 256 + cb + 1], a1);
        atomicAdd(&sums[gfirst * 256 + cb + 2], a2);
        atomicAdd(&sums[gfirst * 256 + cb + 3], a3);
    } else {
        int g = gfirst;
        for (int r = r0; r < r1; r++) {
            int gg = batch[r];
            if (gg != g) {
                atomicAdd(&sums[g * 256 + cb + 0], a0);
                atomicAdd(&sums[g * 256 + cb + 1], a1);
                atomicAdd(&sums[g * 256 + cb + 2], a2);
                atomicAdd(&sums[g * 256 + cb + 3], a3);
                a0 = a1 = a2 = a3 = 0.f; g = gg;
            }
            unsigned q = *(const unsigned*)(h2 + (size_t)r * 256 + cb);
            f32x2 d0 = __builtin_amdgcn_cvt_pk_f32_fp8((int)q, false);
            f32x2 d1 = __builtin_amdgcn_cvt_pk_f32_fp8((int)q, true);
            a0 += d0.x; a1 += d0.y; a2 += d1.x; a3 += d1.y;
        }
        atomicAdd(&sums[g * 256 + cb + 0], a0);
        atomicAdd(&sums[g * 256 + cb + 1], a1);
        atomicAdd(&sums[g * 256 + cb + 2], a2);
        atomicAdd(&sums[g * 256 + cb + 3], a3);
    }
}

// ---------------------------------------------------------------- pooled @ Wl + bl
__global__ void final_kernel(const float* __restrict__ sums, const int* __restrict__ batch,
                             const float* __restrict__ Wl, const float* __restrict__ bl,
                             float* __restrict__ out) {
    int g = blockIdx.x;
    int l = threadIdx.x;
    int lo = 0, hi = NODES;
    while (lo < hi) { int m = (lo + hi) >> 1; if (batch[m] < g) lo = m + 1; else hi = m; }
    int lb = lo;
    lo = lb; hi = NODES;
    while (lo < hi) { int m = (lo + hi) >> 1; if (batch[m] <= g) lo = m + 1; else hi = m; }
    int cnt = lo - lb;
    float inv = 1.f / fmaxf((float)cnt, 1.f);
    float a0 = 0.f, a1 = 0.f;
    for (int k = l; k < 256; k += 64) {
        float p = sums[g * 256 + k] * inv;
        a0 += p * Wl[k * 2 + 0];
        a1 += p * Wl[k * 2 + 1];
    }
    for (int off = 32; off > 0; off >>= 1) {
        a0 += __shfl_down(a0, off, 64);
        a1 += __shfl_down(a1, off, 64);
    }
    if (l == 0) {
        out[g * 2 + 0] = a0 + bl[0];
        out[g * 2 + 1] = a1 + bl[1];
    }
}

// ---------------------------------------------------------------- launch
extern "C" void kernel_launch(void* const* d_in, const int* in_sizes, int n_in,
                              void* d_out, int out_size, void* d_ws, size_t ws_size,
                              hipStream_t stream) {
    const float* x    = (const float*)d_in[0];
    const int*   ei   = (const int*)d_in[1];
    const int*   bat  = (const int*)d_in[2];
    const float* W1   = (const float*)d_in[3];
    const float* b1   = (const float*)d_in[4];
    const float* W2   = (const float*)d_in[5];
    const float* b2   = (const float*)d_in[6];
    const float* Wl   = (const float*)d_in[7];
    const float* bl   = (const float*)d_in[8];
    float*       out  = (float*)d_out;
    const int* erow = ei;           // edge_index[0] = source
    const int* ecol = ei + EDGES;   // edge_index[1] = target

    char* p = (char*)d_ws;
    auto take = [&](size_t bytes) {
        char* r = p;
        p += (bytes + 255) & ~(size_t)255;
        return r;
    };
    float* dinv   = (float*)take((size_t)NODES * 4);
    int*   rowptr = (int*)  take((size_t)(NODES + 1) * 4);
    int*   gcnt   = (int*)  take((size_t)NBUCK * 4);
    int*   csr    = (int*)  take((size_t)ETOT * 4);
    float* sums   = (float*)take((size_t)NGRAPH * HDIM * 4);
    bf16*  W1t    = (bf16*) take((size_t)128 * 256 * 2);
    bf16*  W2t    = (bf16*) take((size_t)256 * 256 * 2);
    char*  reg1   = (char*) take((size_t)NODES * HDIM * 1);   // x8 (4 slabs) -> h1f8 (8 slabs)
    char*  reg2   = (char*) take((size_t)NODES * HDIM * 1);   // aggbuf1 (4 slabs) -> aggbuf2 (8 slabs)
    char*  reg3   = (char*) take((size_t)NODES * HDIM * 1);   // recs (15.3) -> h2f8 (25.6 row-major)
    unsigned char* x8      = (unsigned char*)reg1; // 4 slabs, dead after agg1
    unsigned char* h1f8    = (unsigned char*)reg1; // 8 slabs, born mgemm1, dead after agg2
    unsigned char* aggbuf1 = (unsigned char*)reg2; // 4 slabs, born agg1, dead after mgemm1
    unsigned char* aggbuf2 = (unsigned char*)reg2; // 8 slabs, born agg2, dead after mgemm2
    unsigned*      recs    = (unsigned*)reg3;      // dead after build
    unsigned char* h2f8    = (unsigned char*)reg3; // row-major 256, born mgemm2

    hipMemsetAsync(sums, 0, (size_t)NGRAPH * HDIM * 4, stream);
    hipMemsetAsync(gcnt, 0, (size_t)NBUCK * 4, stream);
    wcast_kernel<<<(128 * 256 + 256 * 256 + 255) / 256, 256, 0, stream>>>(W1, W2, W1t, W2t);

    fillp1_kernel<<<(ETOT + 16383) / 16384, 1024, 0, stream>>>(erow, ecol, gcnt, recs);
    build_kernel <<<NBUCK, 256, 0, stream>>>(recs, gcnt, rowptr, dinv, csr);

    // xcast needs dinv -> after build
    xcast_kernel<<<(NODES * 128 / 4 + 255) / 256, 256, 0, stream>>>(x, dinv, x8);

    const int AGGB = (NODES * 2 + 255) / 256;         // 782 blocks, 128 nodes each
    // layer-1 aggregation: 4 sequential slab passes (3.2 MB table each -> L2-resident)
    for (int s = 0; s < 4; s++)
        aggs_kernel<<<AGGB, 256, 0, stream>>>(x8 + (size_t)s * SLABSZ, rowptr, csr, dinv,
                                              aggbuf1 + (size_t)s * SLABSZ);

    const int MB = (NODES + 127) / 128;               // 782
    mgemm_kernel<128, true,  true ><<<MB * 2, 256, 0, stream>>>(aggbuf1, W1t, b1, dinv, h1f8);

    // layer-2 aggregation: 8 sequential slab passes
    for (int s = 0; s < 8; s++)
        aggs_kernel<<<AGGB, 256, 0, stream>>>(h1f8 + (size_t)s * SLABSZ, rowptr, csr, dinv,
                                              aggbuf2 + (size_t)s * SLABSZ);

    mgemm_kernel<256, false, false><<<MB * 2, 256, 0, stream>>>(aggbuf2, W2t, b2, nullptr, h2f8);

    pool_kernel<<<(NODES + 127) / 128, 256, 0, stream>>>(h2f8, bat, sums);

    final_kernel<<<NGRAPH, 64, 0, stream>>>(sums, bat, Wl, bl, out);
}

// Round 7
// 439.430 us; speedup vs baseline: 1.7066x; 1.7066x over previous
//
#include <hip/hip_runtime.h>
#include <hip/hip_bf16.h>
#include <cstddef>

#define NODES  100000
#define EDGES  3200000
#define ETOT   3300000   // EDGES + NODES self-loops
#define NGRAPH 64
#define HDIM   256
#define BSHIFT 8
#define NBUCK  391       // ceil(NODES / 256)
#define BCAP   10496     // records/bucket: mean 8448 + ~22 sigma

typedef __hip_bfloat16 bf16;
typedef short bf16x8 __attribute__((ext_vector_type(8)));
typedef float f32x4 __attribute__((ext_vector_type(4)));
typedef float f32x2 __attribute__((ext_vector_type(2)));
typedef unsigned u32x2 __attribute__((ext_vector_type(2)));
typedef unsigned u32x4 __attribute__((ext_vector_type(4)));

// ---------------------------------------------------------------- fp32 -> fp8 of x, pre-scaled by dinv[row]
__global__ void xcast_kernel(const float* __restrict__ x, const float* __restrict__ dinv,
                             unsigned char* __restrict__ x8) {
    int i = blockIdx.x * 256 + threadIdx.x;            // 4 elements each
    if ((size_t)i * 4 >= (size_t)NODES * 128) return;
    float d = dinv[i >> 5];                            // 128 cols / 4 = 32 groups per row
    float4 v = *(const float4*)(x + (size_t)i * 4);
    int w = __builtin_amdgcn_cvt_pk_fp8_f32(v.x * d, v.y * d, 0, false);
    w     = __builtin_amdgcn_cvt_pk_fp8_f32(v.z * d, v.w * d, w, true);
    *(unsigned*)(x8 + (size_t)i * 4) = (unsigned)w;
}

// ---------------------------------------------------------------- W1/W2 -> transposed bf16
__global__ void wcast_kernel(const float* __restrict__ W1, const float* __restrict__ W2,
                             bf16* __restrict__ W1t, bf16* __restrict__ W2t) {
    int i = blockIdx.x * 256 + threadIdx.x;
    if (i < 128 * 256) {
        int n = i / 128, k = i - n * 128;
        W1t[i] = __float2bfloat16(W1[(size_t)k * 256 + n]);
    } else if (i < 128 * 256 + 256 * 256) {
        int q = i - 128 * 256;
        int n = q / 256, k = q - n * 256;
        W2t[q] = __float2bfloat16(W2[(size_t)k * 256 + n]);
    }
}

// ---------------------------------------------------------------- fill phase 1: 4-byte bucket records
// rec = (src << 8) | local_dst. 4-copy LDS histogram quarters rank-atomic collisions.
__global__ __launch_bounds__(1024) void fillp1_kernel(const int* __restrict__ row,
                                                      const int* __restrict__ col,
                                                      int* __restrict__ gcnt,
                                                      unsigned* __restrict__ recs) {
    __shared__ int hist[4][NBUCK];
    __shared__ int coff[4][NBUCK];
    __shared__ int base[NBUCK];
    int t  = threadIdx.x;
    int cp = t & 3;
    for (int i = t; i < 4 * NBUCK; i += 1024) ((int*)hist)[i] = 0;
    __syncthreads();
    int e0 = blockIdx.x * 16384;
    int r[16], c[16], rk[16];
    #pragma unroll
    for (int i = 0; i < 16; i++) {
        int e = e0 + i * 1024 + t;
        r[i] = -1;
        if (e < ETOT) {
            if (e < EDGES) { r[i] = row[e]; c[i] = col[e]; }
            else           { r[i] = e - EDGES; c[i] = r[i]; }
            rk[i] = atomicAdd(&hist[cp][c[i] >> BSHIFT], 1);
        }
    }
    __syncthreads();
    for (int b = t; b < NBUCK; b += 1024) {
        int h0 = hist[0][b], h1 = hist[1][b], h2 = hist[2][b], h3 = hist[3][b];
        coff[0][b] = 0; coff[1][b] = h0; coff[2][b] = h0 + h1; coff[3][b] = h0 + h1 + h2;
        int tot = h0 + h1 + h2 + h3;
        base[b] = (tot > 0) ? atomicAdd(&gcnt[b], tot) : 0;
    }
    __syncthreads();
    #pragma unroll
    for (int i = 0; i < 16; i++) {
        if (r[i] >= 0) {
            int b = c[i] >> BSHIFT;
            recs[(size_t)b * BCAP + base[b] + coff[cp][b] + rk[i]] =
                ((unsigned)r[i] << BSHIFT) | (unsigned)(c[i] & 255);
        }
    }
}

// ---------------------------------------------------------------- per-bucket counting sort (256 nodes/bucket)
// bscan folded in: each block prefix-sums gcnt[0..b) itself.
__global__ __launch_bounds__(256) void build_kernel(const unsigned* __restrict__ recs,
                                                    const int* __restrict__ gcnt,
                                                    int* __restrict__ rowptr,
                                                    float* __restrict__ dinv,
                                                    int* __restrict__ csr) {
    __shared__ int hist[256];
    __shared__ int cur[256];
    __shared__ int part[256];
    __shared__ int sbase;
    const int b = blockIdx.x, t = threadIdx.x;
    const int cnt = gcnt[b];
    const int n0 = b << BSHIFT;
    // block-internal exclusive prefix: base = sum gcnt[0..b)  (b < 391 -> 2 strides)
    int pv = (t < b) ? gcnt[t] : 0;
    if (t + 256 < b) pv += gcnt[t + 256];
    part[t] = pv;
    __syncthreads();
    for (int off = 128; off >= 1; off >>= 1) {
        if (t < off) part[t] += part[t + off];
        __syncthreads();
    }
    if (t == 0) sbase = part[0];
    __syncthreads();
    const int base = sbase;
    hist[t] = 0;
    __syncthreads();
    const unsigned* rb = recs + (size_t)b * BCAP;
    for (int i = t; i < cnt; i += 256) atomicAdd(&hist[rb[i] & 255u], 1);
    __syncthreads();
    int h0 = hist[t];
    part[t] = h0;
    __syncthreads();
    for (int off = 1; off < 256; off <<= 1) {
        int v = (t >= off) ? part[t - off] : 0;
        __syncthreads();
        part[t] += v;
        __syncthreads();
    }
    int ex = (t == 0) ? 0 : part[t - 1];       // exclusive over nodes
    cur[t] = ex;
    int v0 = n0 + t;
    if (v0 < NODES) { rowptr[v0] = base + ex; dinv[v0] = rsqrtf((float)h0); }
    if (b == 0 && t == 0) rowptr[NODES] = ETOT;
    __syncthreads();
    for (int i = t; i < cnt; i += 256) {
        unsigned r = rb[i];
        int pos = atomicAdd(&cur[r & 255u], 1);
        csr[base + pos] = (int)(r >> BSHIFT);
    }
}

#define ACC16(q) do {                                                      \
        a[0] += __builtin_amdgcn_cvt_pk_f32_fp8((int)(q).x, false);        \
        a[1] += __builtin_amdgcn_cvt_pk_f32_fp8((int)(q).x, true);         \
        a[2] += __builtin_amdgcn_cvt_pk_f32_fp8((int)(q).y, false);        \
        a[3] += __builtin_amdgcn_cvt_pk_f32_fp8((int)(q).y, true);         \
        a[4] += __builtin_amdgcn_cvt_pk_f32_fp8((int)(q).z, false);        \
        a[5] += __builtin_amdgcn_cvt_pk_f32_fp8((int)(q).z, true);         \
        a[6] += __builtin_amdgcn_cvt_pk_f32_fp8((int)(q).w, false);        \
        a[7] += __builtin_amdgcn_cvt_pk_f32_fp8((int)(q).w, true);         \
    } while (0)

// ---------------------------------------------------------------- pull aggregation, H=128, fp8 in/out
// One node per wave; 8 lane-groups of 8 lanes; 16B/lane loads (8 lanes x 16B = 128B/row).
__global__ void agg1_kernel(const unsigned char* __restrict__ x8, const int* __restrict__ rowptr,
                            const int* __restrict__ csr, const float* __restrict__ dinv,
                            unsigned char* __restrict__ out) {
    int node = (blockIdx.x * blockDim.x + threadIdx.x) >> 6;
    if (node >= NODES) return;
    int lane = threadIdx.x & 63;
    int sub  = lane >> 3, li = lane & 7;
    int beg = rowptr[node], end = rowptr[node + 1];
    float d = dinv[node];
    f32x2 a[8] = {};
    int j = beg;
    int nb = (end - beg) >> 5;
    if (nb > 0) {
        int i0 = csr[j + sub],      i1 = csr[j + 8 + sub];
        int i2 = csr[j + 16 + sub], i3 = csr[j + 24 + sub];
        for (int b = 1; b <= nb; ++b) {
            u32x4 q0 = *(const u32x4*)(x8 + (size_t)i0 * 128 + li * 16);
            u32x4 q1 = *(const u32x4*)(x8 + (size_t)i1 * 128 + li * 16);
            u32x4 q2 = *(const u32x4*)(x8 + (size_t)i2 * 128 + li * 16);
            u32x4 q3 = *(const u32x4*)(x8 + (size_t)i3 * 128 + li * 16);
            j += 32;
            if (b < nb) {
                i0 = csr[j + sub];      i1 = csr[j + 8 + sub];
                i2 = csr[j + 16 + sub]; i3 = csr[j + 24 + sub];
            }
            ACC16(q0); ACC16(q1); ACC16(q2); ACC16(q3);
        }
    }
    for (; j + 7 < end; j += 8) {
        int s = csr[j + sub];
        u32x4 q = *(const u32x4*)(x8 + (size_t)s * 128 + li * 16);
        ACC16(q);
    }
    if (j + sub < end) {
        int s = csr[j + sub];
        u32x4 q = *(const u32x4*)(x8 + (size_t)s * 128 + li * 16);
        ACC16(q);
    }
    // combine the 8 lane-groups: xor 8, 16, 32
    #pragma unroll
    for (int i = 0; i < 8; i++) {
        a[i].x += __shfl_xor(a[i].x, 8, 64);
        a[i].y += __shfl_xor(a[i].y, 8, 64);
        a[i].x += __shfl_xor(a[i].x, 16, 64);
        a[i].y += __shfl_xor(a[i].y, 16, 64);
        a[i].x += __shfl_xor(a[i].x, 32, 64);
        a[i].y += __shfl_xor(a[i].y, 32, 64);
    }
    if (sub == 0) {
        u32x4 o;
        int p;
        p = __builtin_amdgcn_cvt_pk_fp8_f32(a[0].x * d, a[0].y * d, 0, false);
        p = __builtin_amdgcn_cvt_pk_fp8_f32(a[1].x * d, a[1].y * d, p, true);
        o.x = (unsigned)p;
        p = __builtin_amdgcn_cvt_pk_fp8_f32(a[2].x * d, a[2].y * d, 0, false);
        p = __builtin_amdgcn_cvt_pk_fp8_f32(a[3].x * d, a[3].y * d, p, true);
        o.y = (unsigned)p;
        p = __builtin_amdgcn_cvt_pk_fp8_f32(a[4].x * d, a[4].y * d, 0, false);
        p = __builtin_amdgcn_cvt_pk_fp8_f32(a[5].x * d, a[5].y * d, p, true);
        o.z = (unsigned)p;
        p = __builtin_amdgcn_cvt_pk_fp8_f32(a[6].x * d, a[6].y * d, 0, false);
        p = __builtin_amdgcn_cvt_pk_fp8_f32(a[7].x * d, a[7].y * d, p, true);
        o.w = (unsigned)p;
        *(u32x4*)(out + (size_t)node * 128 + li * 16) = o;
    }
}

// ---------------------------------------------------------------- pull aggregation, H=256, fp8 in/out
// One node per wave; 4 lane-groups of 16 lanes; 16B/lane loads (16 lanes x 16B = 256B/row).
__global__ void agg2_kernel(const unsigned char* __restrict__ h8, const int* __restrict__ rowptr,
                            const int* __restrict__ csr, const float* __restrict__ dinv,
                            unsigned char* __restrict__ out) {
    int node = (blockIdx.x * blockDim.x + threadIdx.x) >> 6;
    if (node >= NODES) return;
    int lane = threadIdx.x & 63;
    int sub  = lane >> 4, li = lane & 15;
    int beg = rowptr[node], end = rowptr[node + 1];
    float d = dinv[node];
    f32x2 a[8] = {};
    int j = beg;
    int nb = (end - beg) >> 4;
    if (nb > 0) {
        int i0 = csr[j + sub],     i1 = csr[j + 4 + sub];
        int i2 = csr[j + 8 + sub], i3 = csr[j + 12 + sub];
        for (int b = 1; b <= nb; ++b) {
            u32x4 q0 = *(const u32x4*)(h8 + (size_t)i0 * 256 + li * 16);
            u32x4 q1 = *(const u32x4*)(h8 + (size_t)i1 * 256 + li * 16);
            u32x4 q2 = *(const u32x4*)(h8 + (size_t)i2 * 256 + li * 16);
            u32x4 q3 = *(const u32x4*)(h8 + (size_t)i3 * 256 + li * 16);
            j += 16;
            if (b < nb) {
                i0 = csr[j + sub];     i1 = csr[j + 4 + sub];
                i2 = csr[j + 8 + sub]; i3 = csr[j + 12 + sub];
            }
            ACC16(q0); ACC16(q1); ACC16(q2); ACC16(q3);
        }
    }
    for (; j + 3 < end; j += 4) {
        int s = csr[j + sub];
        u32x4 q = *(const u32x4*)(h8 + (size_t)s * 256 + li * 16);
        ACC16(q);
    }
    if (j + sub < end) {
        int s = csr[j + sub];
        u32x4 q = *(const u32x4*)(h8 + (size_t)s * 256 + li * 16);
        ACC16(q);
    }
    // combine the 4 lane-groups: xor 16, 32
    #pragma unroll
    for (int i = 0; i < 8; i++) {
        a[i].x += __shfl_xor(a[i].x, 16, 64);
        a[i].y += __shfl_xor(a[i].y, 16, 64);
        a[i].x += __shfl_xor(a[i].x, 32, 64);
        a[i].y += __shfl_xor(a[i].y, 32, 64);
    }
    if (sub == 0) {
        u32x4 o;
        int p;
        p = __builtin_amdgcn_cvt_pk_fp8_f32(a[0].x * d, a[0].y * d, 0, false);
        p = __builtin_amdgcn_cvt_pk_fp8_f32(a[1].x * d, a[1].y * d, p, true);
        o.x = (unsigned)p;
        p = __builtin_amdgcn_cvt_pk_fp8_f32(a[2].x * d, a[2].y * d, 0, false);
        p = __builtin_amdgcn_cvt_pk_fp8_f32(a[3].x * d, a[3].y * d, p, true);
        o.y = (unsigned)p;
        p = __builtin_amdgcn_cvt_pk_fp8_f32(a[4].x * d, a[4].y * d, 0, false);
        p = __builtin_amdgcn_cvt_pk_fp8_f32(a[5].x * d, a[5].y * d, p, true);
        o.z = (unsigned)p;
        p = __builtin_amdgcn_cvt_pk_fp8_f32(a[6].x * d, a[6].y * d, 0, false);
        p = __builtin_amdgcn_cvt_pk_fp8_f32(a[7].x * d, a[7].y * d, p, true);
        o.w = (unsigned)p;
        *(u32x4*)(out + (size_t)node * 256 + li * 16) = o;
    }
}
#undef ACC16

// ---------------------------------------------------------------- MFMA GEMM 128x128, fp8 A (decoded), bf16 B
// C[M,256] = relu(A8[M,K] @ B[K,256] + bias) [* dinv[row] if PRESCALE], written fp8 e4m3.
template <int K, bool PRESCALE>
__global__ __launch_bounds__(256) void mgemm_kernel(const unsigned char* __restrict__ A8,
                                                    const bf16* __restrict__ Bt,
                                                    const float* __restrict__ bias,
                                                    const float* __restrict__ dinv,
                                                    unsigned char* __restrict__ C8) {
    __shared__ short As[128][40];   // [m][k] bf16 (decoded from fp8), +8 pad
    __shared__ short Bs[128][40];   // [n][k] bf16
    const int t    = threadIdx.x;
    const int bm   = (int)(blockIdx.x >> 1) * 128;
    const int bn   = (int)(blockIdx.x & 1) * 128;
    const int lane = t & 63;
    const int wave = t >> 6;
    const int wm   = (wave >> 1) * 64, wn = (wave & 1) * 64;
    const int m16  = lane & 15, kq = lane >> 4;
    f32x4 acc[4][4] = {};

    for (int k0 = 0; k0 < K; k0 += 32) {
        // A tile: 128 rows x 32 fp8 = 4 KB, one uint4 (16 fp8) per thread, decode -> bf16 LDS
        {
            int rr = t >> 1, seg = t & 1;          // seg*16 fp8 within the 32-k tile
            uint4 va = {0u, 0u, 0u, 0u};
            int grow = bm + rr;
            if (grow < NODES) va = *(const uint4*)(A8 + (size_t)grow * K + k0 + seg * 16);
            unsigned wd[4] = {va.x, va.y, va.z, va.w};
            #pragma unroll
            for (int u = 0; u < 4; u++) {
                f32x2 lo = __builtin_amdgcn_cvt_pk_f32_fp8((int)wd[u], false);
                f32x2 hi = __builtin_amdgcn_cvt_pk_f32_fp8((int)wd[u], true);
                union { __hip_bfloat162 h[2]; u32x2 q; } pk;
                pk.h[0] = __float22bfloat162_rn(make_float2(lo.x, lo.y));
                pk.h[1] = __float22bfloat162_rn(make_float2(hi.x, hi.y));
                *(u32x2*)&As[rr][seg * 16 + u * 4] = pk.q;
            }
        }
        // B tile: 128 n-rows x 32 k bf16 = 8 KB, two uint4 per thread
        #pragma unroll
        for (int h = 0; h < 2; h++) {
            int q = t * 2 + h;
            int rr = q >> 2, seg = q & 3;
            uint4 vb = *(const uint4*)(Bt + (size_t)(bn + rr) * K + k0 + seg * 8);
            *(uint4*)&Bs[rr][seg * 8] = vb;
        }
        __syncthreads();
        bf16x8 af[4], bf_[4];
        #pragma unroll
        for (int i = 0; i < 4; i++) {
            af[i]  = *(const bf16x8*)&As[wm + i * 16 + m16][kq * 8];
            bf_[i] = *(const bf16x8*)&Bs[wn + i * 16 + m16][kq * 8];
        }
        #pragma unroll
        for (int mt = 0; mt < 4; mt++)
            #pragma unroll
            for (int nt = 0; nt < 4; nt++)
                acc[mt][nt] = __builtin_amdgcn_mfma_f32_16x16x32_bf16(af[mt], bf_[nt],
                                                                     acc[mt][nt], 0, 0, 0);
        __syncthreads();
    }

    // C/D layout: col = lane&15, row = (lane>>4)*4 + reg
    #pragma unroll
    for (int mt = 0; mt < 4; mt++) {
        #pragma unroll
        for (int r = 0; r < 4; r++) {
            int row = bm + wm + mt * 16 + kq * 4 + r;
            if (row >= NODES) continue;
            float sc = PRESCALE ? dinv[row] : 1.f;
            #pragma unroll
            for (int nt = 0; nt < 4; nt++) {
                int colb = bn + wn + nt * 16 + m16;
                float v = fmaxf(acc[mt][nt][r] + bias[colb], 0.f) * sc;
                int pkd = __builtin_amdgcn_cvt_pk_fp8_f32(v, v, 0, false);
                C8[(size_t)row * 256 + colb] = (unsigned char)(pkd & 0xff);
            }
        }
    }
}

// ---------------------------------------------------------------- segmented mean-pool sum (fp8 in)
// 128 rows/block, 32 rows/wave; lane covers 4 cols. Fast path when the wave's
// whole row-range is one graph (~98% of waves): branch-free unrolled loop.
__global__ __launch_bounds__(256) void pool_kernel(const unsigned char* __restrict__ h2,
                                                   const int* __restrict__ batch,
                                                   float* __restrict__ sums) {
    int lane = threadIdx.x & 63;                   // 4 cols each
    int wv   = threadIdx.x >> 6;                   // 0..3
    int r0   = blockIdx.x * 128 + wv * 32;
    if (r0 >= NODES) return;
    int r1 = r0 + 32; if (r1 > NODES) r1 = NODES;
    float a0 = 0.f, a1 = 0.f, a2 = 0.f, a3 = 0.f;
    int cb = lane * 4;
    int gfirst = batch[r0], glast = batch[r1 - 1];
    if (gfirst == glast) {
        #pragma unroll 4
        for (int r = r0; r < r1; r++) {
            unsigned q = *(const unsigned*)(h2 + (size_t)r * 256 + cb);
            f32x2 d0 = __builtin_amdgcn_cvt_pk_f32_fp8((int)q, false);
            f32x2 d1 = __builtin_amdgcn_cvt_pk_f32_fp8((int)q, true);
            a0 += d0.x; a1 += d0.y; a2 += d1.x; a3 += d1.y;
        }
        atomicAdd(&sums[gfirst * 256 + cb + 0], a0);
        atomicAdd(&sums[gfirst * 256 + cb + 1], a1);
        atomicAdd(&sums[gfirst * 256 + cb + 2], a2);
        atomicAdd(&sums[gfirst * 256 + cb + 3], a3);
    } else {
        int g = gfirst;
        for (int r = r0; r < r1; r++) {
            int gg = batch[r];
            if (gg != g) {
                atomicAdd(&sums[g * 256 + cb + 0], a0);
                atomicAdd(&sums[g * 256 + cb + 1], a1);
                atomicAdd(&sums[g * 256 + cb + 2], a2);
                atomicAdd(&sums[g * 256 + cb + 3], a3);
                a0 = a1 = a2 = a3 = 0.f; g = gg;
            }
            unsigned q = *(const unsigned*)(h2 + (size_t)r * 256 + cb);
            f32x2 d0 = __builtin_amdgcn_cvt_pk_f32_fp8((int)q, false);
            f32x2 d1 = __builtin_amdgcn_cvt_pk_f32_fp8((int)q, true);
            a0 += d0.x; a1 += d0.y; a2 += d1.x; a3 += d1.y;
        }
        atomicAdd(&sums[g * 256 + cb + 0], a0);
        atomicAdd(&sums[g * 256 + cb + 1], a1);
        atomicAdd(&sums[g * 256 + cb + 2], a2);
        atomicAdd(&sums[g * 256 + cb + 3], a3);
    }
}

// ---------------------------------------------------------------- pooled @ Wl + bl
__global__ void final_kernel(const float* __restrict__ sums, const int* __restrict__ batch,
                             const float* __restrict__ Wl, const float* __restrict__ bl,
                             float* __restrict__ out) {
    int g = blockIdx.x;
    int l = threadIdx.x;
    int lo = 0, hi = NODES;
    while (lo < hi) { int m = (lo + hi) >> 1; if (batch[m] < g) lo = m + 1; else hi = m; }
    int lb = lo;
    lo = lb; hi = NODES;
    while (lo < hi) { int m = (lo + hi) >> 1; if (batch[m] <= g) lo = m + 1; else hi = m; }
    int cnt = lo - lb;
    float inv = 1.f / fmaxf((float)cnt, 1.f);
    float a0 = 0.f, a1 = 0.f;
    for (int k = l; k < 256; k += 64) {
        float p = sums[g * 256 + k] * inv;
        a0 += p * Wl[k * 2 + 0];
        a1 += p * Wl[k * 2 + 1];
    }
    for (int off = 32; off > 0; off >>= 1) {
        a0 += __shfl_down(a0, off, 64);
        a1 += __shfl_down(a1, off, 64);
    }
    if (l == 0) {
        out[g * 2 + 0] = a0 + bl[0];
        out[g * 2 + 1] = a1 + bl[1];
    }
}

// ---------------------------------------------------------------- launch
extern "C" void kernel_launch(void* const* d_in, const int* in_sizes, int n_in,
                              void* d_out, int out_size, void* d_ws, size_t ws_size,
                              hipStream_t stream) {
    const float* x    = (const float*)d_in[0];
    const int*   ei   = (const int*)d_in[1];
    const int*   bat  = (const int*)d_in[2];
    const float* W1   = (const float*)d_in[3];
    const float* b1   = (const float*)d_in[4];
    const float* W2   = (const float*)d_in[5];
    const float* b2   = (const float*)d_in[6];
    const float* Wl   = (const float*)d_in[7];
    const float* bl   = (const float*)d_in[8];
    float*       out  = (float*)d_out;
    const int* erow = ei;           // edge_index[0] = source
    const int* ecol = ei + EDGES;   // edge_index[1] = target

    char* p = (char*)d_ws;
    auto take = [&](size_t bytes) {
        char* r = p;
        p += (bytes + 255) & ~(size_t)255;
        return r;
    };
    float* dinv   = (float*)take((size_t)NODES * 4);
    int*   rowptr = (int*)  take((size_t)(NODES + 1) * 4);
    int*   gcnt   = (int*)  take((size_t)NBUCK * 4);
    int*   csr    = (int*)  take((size_t)ETOT * 4);
    float* sums   = (float*)take((size_t)NGRAPH * HDIM * 4);
    bf16*  W1t    = (bf16*) take((size_t)128 * 256 * 2);
    bf16*  W2t    = (bf16*) take((size_t)256 * 256 * 2);
    char*  reg1   = (char*) take((size_t)NODES * HDIM * 1);   // x8 (12.8) -> h1f8 (25.6)
    char*  reg2   = (char*) take((size_t)NODES * HDIM * 1);   // aggbuf1 (12.8) -> aggbuf2 (25.6)
    char*  reg3   = (char*) take((size_t)NODES * HDIM * 1);   // recs (16.4) -> h2f8 (25.6)
    unsigned char* x8      = (unsigned char*)reg1; // dead after agg1
    unsigned char* h1f8    = (unsigned char*)reg1; // born mgemm1, dead after agg2
    unsigned char* aggbuf1 = (unsigned char*)reg2; // born agg1, dead after mgemm1
    unsigned char* aggbuf2 = (unsigned char*)reg2; // born agg2, dead after mgemm2
    unsigned*      recs    = (unsigned*)reg3;      // dead after build
    unsigned char* h2f8    = (unsigned char*)reg3; // born mgemm2

    hipMemsetAsync(sums, 0, (size_t)NGRAPH * HDIM * 4, stream);
    hipMemsetAsync(gcnt, 0, (size_t)NBUCK * 4, stream);
    wcast_kernel<<<(128 * 256 + 256 * 256 + 255) / 256, 256, 0, stream>>>(W1, W2, W1t, W2t);

    fillp1_kernel<<<(ETOT + 16383) / 16384, 1024, 0, stream>>>(erow, ecol, gcnt, recs);
    build_kernel <<<NBUCK, 256, 0, stream>>>(recs, gcnt, rowptr, dinv, csr);

    // xcast needs dinv -> after build
    xcast_kernel<<<(NODES * 128 / 4 + 255) / 256, 256, 0, stream>>>(x, dinv, x8);

    const int AGG_BLOCKS = ((size_t)NODES * 64 + 255) / 256;  // 1 node per wave
    agg1_kernel<<<AGG_BLOCKS, 256, 0, stream>>>(x8, rowptr, csr, dinv, aggbuf1);

    const int MB = (NODES + 127) / 128;               // 782
    mgemm_kernel<128, true ><<<MB * 2, 256, 0, stream>>>(aggbuf1, W1t, b1, dinv, h1f8);

    agg2_kernel<<<AGG_BLOCKS, 256, 0, stream>>>(h1f8, rowptr, csr, dinv, aggbuf2);

    mgemm_kernel<256, false><<<MB * 2, 256, 0, stream>>>(aggbuf2, W2t, b2, nullptr, h2f8);

    pool_kernel<<<(NODES + 127) / 128, 256, 0, stream>>>(h2f8, bat, sums);

    final_kernel<<<NGRAPH, 64, 0, stream>>>(sums, bat, Wl, bl, out);
}